// Round 1
// baseline (453.633 us; speedup 1.0000x reference)
//
#include <hip/hip_runtime.h>

// IterNorm (ZCA whitening via Newton-Schulz) for X[64,256,56,56] fp32, d=64, g=4, T=10.
//
//  K1 cov_kernel   : fused mean+cov partials, bf16 MFMA SYRK. grid 1024, reg-prefetch
//                    pipeline with lgkm-only barriers (global loads stay in flight).
//  K2a mean_kernel : reduce per-block channel sums -> mean. grid 4.
//  K2b sigma_kernel: reduce cov partials -> Sigma = E[xx]/m - mu mu^T + eps I. grid 256.
//  K3 newton_kernel: 10 Newton iters, split-bf16 in SEPARATE hi/lo LDS planes (no
//                    unpack VALU), symmetric-transpose C writes (b64), 3 barriers/iter.
//  K4 apply_kernel : out = (wm @ (x-mean)) * weight + bias. grid 1024, same pipeline.
//
// MFMA 16x16x32 bf16 layouts (verified round 1):
//   A: lane l holds A[m=l&15][k=(l>>4)*8+j]   B: lane l holds B[k=(l>>4)*8+j][n=l&15]
//   C/D: lane l reg r -> row=(l>>4)*4+r, col=l&15

#define HWSZ 3136
#define CCH 256
#define DCH 64
#define MTOT (64 * HWSZ) /* 200704 */
#define EPSV 1e-5f
#define TST 68 /* tile row stride in shorts; uint2 accesses stay 8B-aligned */
#define NST 68

typedef __attribute__((ext_vector_type(8))) short short8v;
typedef __attribute__((ext_vector_type(4))) float floatx4;

union F8U {
  short8v v;
  unsigned u[4];
  uint2 u2[2];
};

__device__ __forceinline__ unsigned short f2bf(float f) {
  unsigned u = __float_as_uint(f);
  u += 0x7fffu + ((u >> 16) & 1u);
  return (unsigned short)(u >> 16);
}
__device__ __forceinline__ float bf2f(unsigned short h) {
  return __uint_as_float(((unsigned)h) << 16);
}

// Workgroup barrier that waits LDS only: leaves global loads/stores in flight
// (__syncthreads would emit s_waitcnt vmcnt(0) and kill the prefetch overlap).
__device__ __forceinline__ void sync_lds() {
  asm volatile("s_waitcnt lgkmcnt(0)\n\ts_barrier" ::: "memory");
}

// ---------------- K1: mean + covariance partials ----------------
// grid 1024 = 4 groups x 64 n x 4 hw-quarters (12/12/12/13 k-steps of 64 hw).
__global__ __launch_bounds__(256) void cov_kernel(const float* __restrict__ X,
                                                  float* __restrict__ cov_dst,
                                                  float* __restrict__ sum_dst, int use_part) {
  __shared__ unsigned short tile[64 * TST];
  int bid = blockIdx.x;
  int g = bid >> 8;
  int nn = (bid >> 2) & 63;
  int qh = bid & 3;
  int ks0 = (qh * 49) >> 2;       // 0,12,24,36
  int ks1 = ((qh + 1) * 49) >> 2; // 12,24,36,49
  int tid = threadIdx.x;
  int c = tid >> 2, q = tid & 3;
  int w = tid >> 6, lane = tid & 63, quad = lane >> 4, lm = lane & 15;

  floatx4 acc[4];
#pragma unroll
  for (int tj = 0; tj < 4; tj++) {
    floatx4 z = {0.f, 0.f, 0.f, 0.f};
    acc[tj] = z;
  }
  float fsum = 0.f;

  const float* xbase = X + ((size_t)(nn * CCH + g * DCH + c)) * HWSZ;

  float4 v[4];
  {
    int k0 = ks0 * 64;
#pragma unroll
    for (int j = 0; j < 4; j++) v[j] = *(const float4*)(xbase + k0 + j * 16 + q * 4);
  }

  for (int ks = ks0; ks < ks1; ks++) {
    // stage current tile (consumes prefetch regs)
#pragma unroll
    for (int j = 0; j < 4; j++) {
      float4 t = v[j];
      fsum += t.x + t.y + t.z + t.w;
      unsigned d0 = (unsigned)f2bf(t.x) | ((unsigned)f2bf(t.y) << 16);
      unsigned d1 = (unsigned)f2bf(t.z) | ((unsigned)f2bf(t.w) << 16);
      *(uint2*)&tile[c * TST + j * 16 + q * 4] = make_uint2(d0, d1);
    }
    sync_lds();
    // prefetch next tile -- overlaps the MFMA phase below
    if (ks + 1 < ks1) {
      int k0 = (ks + 1) * 64;
#pragma unroll
      for (int j = 0; j < 4; j++) v[j] = *(const float4*)(xbase + k0 + j * 16 + q * 4);
    }
#pragma unroll
    for (int kk = 0; kk < 2; kk++) {
      F8U a;
      a.u2[0] = *(const uint2*)&tile[(16 * w + lm) * TST + kk * 32 + quad * 8];
      a.u2[1] = *(const uint2*)&tile[(16 * w + lm) * TST + kk * 32 + quad * 8 + 4];
#pragma unroll
      for (int tj = 0; tj < 4; tj++) {
        F8U b;
        b.u2[0] = *(const uint2*)&tile[(16 * tj + lm) * TST + kk * 32 + quad * 8];
        b.u2[1] = *(const uint2*)&tile[(16 * tj + lm) * TST + kk * 32 + quad * 8 + 4];
        acc[tj] = __builtin_amdgcn_mfma_f32_16x16x32_bf16(a.v, b.v, acc[tj], 0, 0, 0);
      }
    }
    sync_lds(); // reads done (consumed by MFMA); next iter may overwrite tile
  }

  int pidx = bid & 255;
  if (use_part) {
    float* dst = cov_dst + ((size_t)g * 256 + pidx) * 4096;
#pragma unroll
    for (int tj = 0; tj < 4; tj++)
#pragma unroll
      for (int rr = 0; rr < 4; rr++)
        dst[(16 * w + quad * 4 + rr) * 64 + 16 * tj + lm] = acc[tj][rr];
  } else {
    float* dst = cov_dst + (size_t)g * 4096;
#pragma unroll
    for (int tj = 0; tj < 4; tj++)
#pragma unroll
      for (int rr = 0; rr < 4; rr++)
        atomicAdd(&dst[(16 * w + quad * 4 + rr) * 64 + 16 * tj + lm], acc[tj][rr]);
  }

  fsum += __shfl_xor(fsum, 1);
  fsum += __shfl_xor(fsum, 2);
  if (q == 0) {
    if (use_part)
      sum_dst[((size_t)g * 256 + pidx) * 64 + c] = fsum;
    else
      atomicAdd(&sum_dst[g * 64 + c], fsum);
  }
}

// ---------------- K2a: channel means ----------------
__global__ __launch_bounds__(256) void mean_kernel(const float* __restrict__ sum_part,
                                                   float* __restrict__ meanWS, int npart) {
  __shared__ float red[256];
  int g = blockIdx.x, tid = threadIdx.x;
  int c = tid & 63, p0 = tid >> 6;
  float s0 = 0.f, s1 = 0.f;
  for (int p = p0; p + 4 < npart; p += 8) {
    s0 += sum_part[((size_t)g * npart + p) * 64 + c];
    s1 += sum_part[((size_t)g * npart + p + 4) * 64 + c];
  }
  for (int p = p0 + ((npart - p0 + 7) / 8) * 8 - 8 + 8; p < npart; p += 4) s0 += 0.f; // no-op guard
  // handle tail (npart multiple of 4 in both paths; loop above covers pairs)
  if (((npart >> 2) & 1) && (p0 + ((npart >> 2) - 1) * 4 < npart)) {
    int p = ((npart >> 2) - 1) * 4 + p0;
    if (p < npart) s0 += sum_part[((size_t)g * npart + p) * 64 + c];
  }
  red[tid] = s0 + s1;
  __syncthreads();
  if (tid < 64)
    meanWS[g * 64 + tid] =
        (red[tid] + red[tid + 64] + red[tid + 128] + red[tid + 192]) / (float)MTOT;
}

// ---------------- K2b: Sigma ----------------
// grid 256 = 4 groups x 64 rows; 4 threads per element, npart/4 parts each.
__global__ __launch_bounds__(256) void sigma_kernel(const float* __restrict__ cov_part,
                                                    const float* __restrict__ meanWS,
                                                    float* __restrict__ Sigma, int npart) {
  __shared__ float red[256];
  int b = blockIdx.x;
  int g = b >> 6, r = b & 63;
  int tid = threadIdx.x;
  int e = tid & 63, p0 = tid >> 6;
  float s = 0.f;
  for (int p = p0; p < npart; p += 4)
    s += cov_part[((size_t)g * npart + p) * 4096 + r * 64 + e];
  red[tid] = s;
  __syncthreads();
  if (tid < 64) {
    float tot = red[tid] + red[tid + 64] + red[tid + 128] + red[tid + 192];
    float mr = meanWS[g * 64 + r], me = meanWS[g * 64 + tid];
    Sigma[(size_t)g * 4096 + r * 64 + tid] =
        tot / (float)MTOT - mr * me + (r == tid ? EPSV : 0.f);
  }
}

// ---------------- K3: Newton-Schulz, hi/lo planes ----------------
// All operands symmetric & commuting: store value(r,c) at plane[c*NST+r]
// (transposed == itself), so C/D writes are column-contiguous b64 stores and
// A/B fragment reads are contiguous row reads. 3 mms, 3 barriers per iter.
__device__ __forceinline__ void mm_planes(floatx4 acc[4], const unsigned short* Ah,
                                          const unsigned short* Al, const unsigned short* Bh,
                                          const unsigned short* Bl, int w, int quad, int lm) {
#pragma unroll
  for (int tj = 0; tj < 4; tj++) {
    floatx4 z = {0.f, 0.f, 0.f, 0.f};
    acc[tj] = z;
  }
#pragma unroll
  for (int kk = 0; kk < 2; kk++) {
    int abase = (16 * w + lm) * NST + kk * 32 + quad * 8;
    F8U ahi, alo;
    ahi.u2[0] = *(const uint2*)&Ah[abase];
    ahi.u2[1] = *(const uint2*)&Ah[abase + 4];
    alo.u2[0] = *(const uint2*)&Al[abase];
    alo.u2[1] = *(const uint2*)&Al[abase + 4];
#pragma unroll
    for (int tj = 0; tj < 4; tj++) {
      int bbase = (16 * tj + lm) * NST + kk * 32 + quad * 8;
      F8U bhi, blo;
      bhi.u2[0] = *(const uint2*)&Bh[bbase];
      bhi.u2[1] = *(const uint2*)&Bh[bbase + 4];
      blo.u2[0] = *(const uint2*)&Bl[bbase];
      blo.u2[1] = *(const uint2*)&Bl[bbase + 4];
      acc[tj] = __builtin_amdgcn_mfma_f32_16x16x32_bf16(ahi.v, bhi.v, acc[tj], 0, 0, 0);
      acc[tj] = __builtin_amdgcn_mfma_f32_16x16x32_bf16(ahi.v, blo.v, acc[tj], 0, 0, 0);
      acc[tj] = __builtin_amdgcn_mfma_f32_16x16x32_bf16(alo.v, bhi.v, acc[tj], 0, 0, 0);
    }
  }
}

__device__ __forceinline__ void store_tr(const floatx4 acc[4], unsigned short* H,
                                         unsigned short* L, int w, int quad, int lm) {
#pragma unroll
  for (int tj = 0; tj < 4; tj++) {
    unsigned short hs[4], ls[4];
#pragma unroll
    for (int rr = 0; rr < 4; rr++) {
      float f = acc[tj][rr];
      hs[rr] = f2bf(f);
      ls[rr] = f2bf(f - bf2f(hs[rr]));
    }
    int a = (16 * tj + lm) * NST + 16 * w + quad * 4;
    *(uint2*)&H[a] = make_uint2((unsigned)hs[0] | ((unsigned)hs[1] << 16),
                                (unsigned)hs[2] | ((unsigned)hs[3] << 16));
    *(uint2*)&L[a] = make_uint2((unsigned)ls[0] | ((unsigned)ls[1] << 16),
                                (unsigned)ls[2] | ((unsigned)ls[3] << 16));
  }
}

__global__ __launch_bounds__(256) void newton_kernel(const float* __restrict__ Sigma,
                                                     unsigned short* __restrict__ wmB) {
  __shared__ unsigned short Ph[64 * NST], Pl[64 * NST];
  __shared__ unsigned short Sh[64 * NST], Sl[64 * NST];
  __shared__ unsigned short Th[64 * NST], Tl[64 * NST];
  __shared__ unsigned short Uh[64 * NST], Ul[64 * NST];
  __shared__ float diag[64];
  int g = blockIdx.x, tid = threadIdx.x;
  int w = tid >> 6, lane = tid & 63, quad = lane >> 4, lm = lane & 15;
  const float* Sg = Sigma + (size_t)g * 4096;

  if (tid < 64) diag[tid] = Sg[tid * 65];
  __syncthreads();
  float tr = 0.f;
#pragma unroll 8
  for (int i = 0; i < 64; i++) tr += diag[i];
  float rTr = 1.0f / tr;

  for (int idx = tid; idx < 4096; idx += 256) {
    int r = idx >> 6, c2 = idx & 63;
    float vv = Sg[idx] * rTr;
    unsigned short h = f2bf(vv);
    Sh[r * NST + c2] = h;
    Sl[r * NST + c2] = f2bf(vv - bf2f(h));
    Ph[r * NST + c2] = (r == c2) ? (unsigned short)0x3f80 : (unsigned short)0;
    Pl[r * NST + c2] = 0;
  }
  sync_lds();

  floatx4 acc[4];
  float pf[4][4];

  for (int t = 0; t < 10; t++) {
    mm_planes(acc, Ph, Pl, Ph, Pl, w, quad, lm); // T = P*P
    store_tr(acc, Th, Tl, w, quad, lm);
    sync_lds();
    mm_planes(acc, Th, Tl, Ph, Pl, w, quad, lm); // U = P^3
    store_tr(acc, Uh, Ul, w, quad, lm);
    sync_lds();
    mm_planes(acc, Uh, Ul, Sh, Sl, w, quad, lm); // P^3 * Sigma_N
    // newP = 1.5*P - 0.5*acc ; each lane owns exactly the elements it rewrites
#pragma unroll
    for (int tj = 0; tj < 4; tj++) {
      int a = (16 * tj + lm) * NST + 16 * w + quad * 4;
      uint2 ho = *(const uint2*)&Ph[a];
      uint2 lo = *(const uint2*)&Pl[a];
      unsigned short hs[4] = {(unsigned short)(ho.x & 0xffff), (unsigned short)(ho.x >> 16),
                              (unsigned short)(ho.y & 0xffff), (unsigned short)(ho.y >> 16)};
      unsigned short lss[4] = {(unsigned short)(lo.x & 0xffff), (unsigned short)(lo.x >> 16),
                               (unsigned short)(lo.y & 0xffff), (unsigned short)(lo.y >> 16)};
      unsigned short nh[4], nl[4];
#pragma unroll
      for (int rr = 0; rr < 4; rr++) {
        float pown = bf2f(hs[rr]) + bf2f(lss[rr]);
        float f = 1.5f * pown - 0.5f * acc[tj][rr];
        pf[tj][rr] = f;
        nh[rr] = f2bf(f);
        nl[rr] = f2bf(f - bf2f(nh[rr]));
      }
      *(uint2*)&Ph[a] = make_uint2((unsigned)nh[0] | ((unsigned)nh[1] << 16),
                                   (unsigned)nh[2] | ((unsigned)nh[3] << 16));
      *(uint2*)&Pl[a] = make_uint2((unsigned)nl[0] | ((unsigned)nl[1] << 16),
                                   (unsigned)nl[2] | ((unsigned)nl[3] << 16));
    }
    sync_lds();
  }

  // wm = P * sqrt(rTr), written straight from the last iteration's registers
  float sc = sqrtf(rTr);
  unsigned short* wg = wmB + (size_t)g * 4096;
#pragma unroll
  for (int tj = 0; tj < 4; tj++)
#pragma unroll
    for (int rr = 0; rr < 4; rr++) {
      int row = 16 * w + quad * 4 + rr, col = 16 * tj + lm;
      wg[row * 64 + col] = f2bf(pf[tj][rr] * sc);
    }
}

// ---------------- K4: apply whitening ----------------
__global__ __launch_bounds__(256) void apply_kernel(
    const float* __restrict__ X, const unsigned short* __restrict__ wmB,
    const float* __restrict__ meanWS, const float* __restrict__ weight,
    const float* __restrict__ bias, float* __restrict__ out) {
  __shared__ unsigned short T[64 * TST];
  __shared__ float meanv[64], wv[64], bv[64];
  int bid = blockIdx.x;
  int g = bid >> 8;
  int nn = (bid >> 2) & 63;
  int qh = bid & 3;
  int ks0 = (qh * 49) >> 2;
  int ks1 = ((qh + 1) * 49) >> 2;
  int tid = threadIdx.x;
  int w = tid >> 6, lane = tid & 63, quad = lane >> 4, lm = lane & 15;
  int sl = tid & 63;
  int cg = tid >> 6;

  if (tid < 64) {
    meanv[tid] = meanWS[g * 64 + tid];
    wv[tid] = weight[g * 64 + tid];
    bv[tid] = bias[g * 64 + tid];
  }
  F8U afrag[2];
#pragma unroll
  for (int kk = 0; kk < 2; kk++) {
    const uint2* p =
        (const uint2*)&wmB[(size_t)g * 4096 + (16 * w + lm) * 64 + kk * 32 + quad * 8];
    afrag[kk].u2[0] = p[0];
    afrag[kk].u2[1] = p[1];
  }
  __syncthreads();

  const float* xg = X + ((size_t)(nn * CCH + g * DCH)) * HWSZ;
  float* og = out + ((size_t)(nn * CCH + g * DCH)) * HWSZ;
  const float* xs = xg + (size_t)(cg * 16) * HWSZ + sl;

  float vv[16];
  {
    int k0 = ks0 * 64;
#pragma unroll
    for (int jp = 0; jp < 16; jp++) vv[jp] = xs[(size_t)jp * HWSZ + k0];
  }

  for (int ks = ks0; ks < ks1; ks++) {
    int k0 = ks * 64;
    // pack current tile (transposed [sample][channel]), consuming prefetch regs
#pragma unroll
    for (int p2 = 0; p2 < 4; p2++) {
      unsigned d0 = (unsigned)f2bf(vv[4 * p2] - meanv[cg * 16 + 4 * p2]) |
                    ((unsigned)f2bf(vv[4 * p2 + 1] - meanv[cg * 16 + 4 * p2 + 1]) << 16);
      unsigned d1 = (unsigned)f2bf(vv[4 * p2 + 2] - meanv[cg * 16 + 4 * p2 + 2]) |
                    ((unsigned)f2bf(vv[4 * p2 + 3] - meanv[cg * 16 + 4 * p2 + 3]) << 16);
      *(uint2*)&T[sl * TST + cg * 16 + p2 * 4] = make_uint2(d0, d1);
    }
    sync_lds();
    // prefetch next tile -- overlaps MFMA + epilogue stores
    if (ks + 1 < ks1) {
      int k0n = (ks + 1) * 64;
#pragma unroll
      for (int jp = 0; jp < 16; jp++) vv[jp] = xs[(size_t)jp * HWSZ + k0n];
    }
    floatx4 acc[4];
#pragma unroll
    for (int tj = 0; tj < 4; tj++) {
      floatx4 z = {0.f, 0.f, 0.f, 0.f};
      acc[tj] = z;
    }
#pragma unroll
    for (int kk = 0; kk < 2; kk++) {
#pragma unroll
      for (int tj = 0; tj < 4; tj++) {
        F8U b;
        b.u2[0] = *(const uint2*)&T[(16 * tj + lm) * TST + kk * 32 + quad * 8];
        b.u2[1] = *(const uint2*)&T[(16 * tj + lm) * TST + kk * 32 + quad * 8 + 4];
        acc[tj] = __builtin_amdgcn_mfma_f32_16x16x32_bf16(afrag[kk].v, b.v, acc[tj], 0, 0, 0);
      }
    }
#pragma unroll
    for (int tj = 0; tj < 4; tj++)
#pragma unroll
      for (int rr = 0; rr < 4; rr++) {
        int cc = 16 * w + quad * 4 + rr;
        og[(size_t)cc * HWSZ + k0 + 16 * tj + lm] = acc[tj][rr] * wv[cc] + bv[cc];
      }
    sync_lds(); // LDS reads consumed; stores stay in flight
  }
}

extern "C" void kernel_launch(void* const* d_in, const int* in_sizes, int n_in, void* d_out,
                              int out_size, void* d_ws, size_t ws_size, hipStream_t stream) {
  (void)in_sizes;
  (void)n_in;
  (void)out_size;
  const float* X = (const float*)d_in[0];
  const float* weight = (const float*)d_in[1];
  const float* bias = (const float*)d_in[2];
  float* out = (float*)d_out;
  char* ws = (char*)d_ws;

  // ws layout: Sigma @0 (64KB) | mean @65536 (1KB) | wmB @66560 (32KB)
  //            cov partials @99328 (4*256*4096*4 = 16MB) | sum partials (+16777216, 256KB)
  float* Sigma = (float*)(ws + 0);
  float* meanWS = (float*)(ws + 65536);
  unsigned short* wmB = (unsigned short*)(ws + 66560);
  float* cov_dst = (float*)(ws + 99328);
  const size_t need_part = 99328u + 16777216u + 262144u;
  int use_part = (ws_size >= need_part) ? 1 : 0;
  float* sum_dst =
      use_part ? (float*)(ws + 99328 + 16777216) : (float*)(ws + 99328 + 65536);
  int npart = use_part ? 256 : 1;

  if (!use_part) {
    hipMemsetAsync(cov_dst, 0, 65536 + 1024, stream);
  }

  cov_kernel<<<dim3(1024), dim3(256), 0, stream>>>(X, cov_dst, sum_dst, use_part);
  mean_kernel<<<dim3(4), dim3(256), 0, stream>>>(sum_dst, meanWS, npart);
  sigma_kernel<<<dim3(256), dim3(256), 0, stream>>>(cov_dst, meanWS, Sigma, npart);
  newton_kernel<<<dim3(4), dim3(256), 0, stream>>>(Sigma, wmB);
  apply_kernel<<<dim3(1024), dim3(256), 0, stream>>>(X, wmB, meanWS, weight, bias, out);
}